// Round 10
// baseline (278.455 us; speedup 1.0000x reference)
//
#include <hip/hip_runtime.h>

typedef __bf16 bf16;
typedef bf16 bf16x8 __attribute__((ext_vector_type(8)));
typedef float f32x4 __attribute__((ext_vector_type(4)));

#define MFMA16(A, B, C) __builtin_amdgcn_mfma_f32_16x16x32_bf16(A, B, C, 0, 0, 0)
#define NEG_BIG -30000.0f

// ---------------------------------------------------------------------------
// Marker: encode a host-side diagnostic into the output (absmax decodes it).
// ---------------------------------------------------------------------------
__global__ void mark_k(float* __restrict__ out, float val, int n) {
    int i = blockIdx.x * 256 + threadIdx.x;
    if (i < n) out[i] = val;
}

// ---------------------------------------------------------------------------
// Weight transpose + f32->bf16: dst[c*R + r] = (bf16)src[r*C + c]
// ---------------------------------------------------------------------------
__global__ void transpose_cvt_k(const float* __restrict__ src, bf16* __restrict__ dst,
                                int R, int C) {
    int i = blockIdx.x * 256 + threadIdx.x;
    if (i >= R * C) return;
    int r = i / C, c = i % C;
    dst[(size_t)c * R + r] = (bf16)src[i];
}

#define LDSK 40  // padded LDS leading dim (32 + 8), 16B-aligned rows

// ---------------------------------------------------------------------------
// QKV GEMM: A = x (f32, 4096x768), B = wqkvT (bf16, 2304x768 = w_qkv^T),
// bias f32. Fused head-reshape epilogue: Q,K:(BH,L,64); V^T:(BH,64,L), bf16.
// 128x128 tile, 4 waves (2x2), 4x4 MFMA tiles/wave, BK=32.
// (MFMA path == scalar path verified on-device in round 8.)
// ---------------------------------------------------------------------------
__global__ __launch_bounds__(256) void gemm_qkv_fused(
    const float* __restrict__ A, const bf16* __restrict__ B,
    const float* __restrict__ bias, bf16* __restrict__ Qh,
    bf16* __restrict__ Kh, bf16* __restrict__ Vth) {
    __shared__ __align__(16) bf16 As[128 * LDSK];
    __shared__ __align__(16) bf16 Bs[128 * LDSK];

    int tid = threadIdx.x, lane = tid & 63, wave = tid >> 6;
    int quad = lane >> 4, l16 = lane & 15;
    int wr = wave >> 1, wc = wave & 1;
    int m0 = blockIdx.y * 128, n0 = blockIdx.x * 128;
    const int K = 768;

    const f32x4 fz = {0.f, 0.f, 0.f, 0.f};
    f32x4 acc[4][4];
#pragma unroll
    for (int mi = 0; mi < 4; ++mi)
#pragma unroll
        for (int nj = 0; nj < 4; ++nj) acc[mi][nj] = fz;

    const float* Ablk = A + (size_t)m0 * K;
    const bf16*  Bblk = B + (size_t)n0 * K;
    int lrow = tid >> 2;           // 0..63
    int lkc  = (tid & 3) * 8;      // 0,8,16,24

    for (int k0 = 0; k0 < K; k0 += 32) {
        __syncthreads();
#pragma unroll
        for (int i = 0; i < 2; ++i) {
            int row = lrow + i * 64;
            const float* ap = &Ablk[(size_t)row * K + k0 + lkc];
            float4 v0 = *(const float4*)ap;
            float4 v1 = *(const float4*)(ap + 4);
            bf16x8 w;
            w[0] = (bf16)v0.x; w[1] = (bf16)v0.y; w[2] = (bf16)v0.z; w[3] = (bf16)v0.w;
            w[4] = (bf16)v1.x; w[5] = (bf16)v1.y; w[6] = (bf16)v1.z; w[7] = (bf16)v1.w;
            *(bf16x8*)&As[row * LDSK + lkc] = w;
            *(bf16x8*)&Bs[row * LDSK + lkc] =
                *(const bf16x8*)&Bblk[(size_t)row * K + k0 + lkc];
        }
        __syncthreads();

        bf16x8 af[4], bfv[4];
#pragma unroll
        for (int t = 0; t < 4; ++t) {
            af[t]  = *(const bf16x8*)&As[(wr * 64 + t * 16 + l16) * LDSK + quad * 8];
            bfv[t] = *(const bf16x8*)&Bs[(wc * 64 + t * 16 + l16) * LDSK + quad * 8];
        }
#pragma unroll
        for (int mi = 0; mi < 4; ++mi)
#pragma unroll
            for (int nj = 0; nj < 4; ++nj)
                acc[mi][nj] = MFMA16(af[mi], bfv[nj], acc[mi][nj]);
    }

#pragma unroll
    for (int nj = 0; nj < 4; ++nj) {
        int col = n0 + wc * 64 + nj * 16 + l16;   // 0..2303
        float bv = bias[col];
        int which = col / 768;
        int rr = col % 768;
        int h = rr >> 6, d = rr & 63;
#pragma unroll
        for (int mi = 0; mi < 4; ++mi)
#pragma unroll
            for (int r = 0; r < 4; ++r) {
                int row = m0 + wr * 64 + mi * 16 + quad * 4 + r;  // 0..4095
                int b = row >> 11, l = row & 2047;
                size_t bh = (size_t)(b * 12 + h);
                bf16 val = (bf16)(acc[mi][nj][r] + bv);
                if (which == 0)      Qh[(bh * 2048 + l) * 64 + d] = val;
                else if (which == 1) Kh[(bh * 2048 + l) * 64 + d] = val;
                else                 Vth[(bh * 64 + d) * 2048 + l] = val;
            }
    }
}

// ---------------------------------------------------------------------------
// Out-projection GEMM: out(F32) = ctx (bf16) @ woutT^T + b_out (f32).
// ---------------------------------------------------------------------------
__global__ __launch_bounds__(256) void gemm_out_f32(
    const bf16* __restrict__ A, const bf16* __restrict__ B,
    const float* __restrict__ bias, float* __restrict__ C,
    int M, int N, int K) {
    __shared__ __align__(16) bf16 As[128 * LDSK];
    __shared__ __align__(16) bf16 Bs[128 * LDSK];

    int tid = threadIdx.x, lane = tid & 63, wave = tid >> 6;
    int quad = lane >> 4, l16 = lane & 15;
    int wr = wave >> 1, wc = wave & 1;
    int m0 = blockIdx.y * 128, n0 = blockIdx.x * 128;

    const f32x4 fz = {0.f, 0.f, 0.f, 0.f};
    f32x4 acc[4][4];
#pragma unroll
    for (int mi = 0; mi < 4; ++mi)
#pragma unroll
        for (int nj = 0; nj < 4; ++nj) acc[mi][nj] = fz;

    const bf16* Ablk = A + (size_t)m0 * K;
    const bf16* Bblk = B + (size_t)n0 * K;
    int lrow = tid >> 2;
    int lkc  = (tid & 3) * 8;

    for (int k0 = 0; k0 < K; k0 += 32) {
        __syncthreads();
#pragma unroll
        for (int i = 0; i < 2; ++i) {
            int row = lrow + i * 64;
            *(bf16x8*)&As[row * LDSK + lkc] =
                *(const bf16x8*)&Ablk[(size_t)row * K + k0 + lkc];
            *(bf16x8*)&Bs[row * LDSK + lkc] =
                *(const bf16x8*)&Bblk[(size_t)row * K + k0 + lkc];
        }
        __syncthreads();

        bf16x8 af[4], bfv[4];
#pragma unroll
        for (int t = 0; t < 4; ++t) {
            af[t]  = *(const bf16x8*)&As[(wr * 64 + t * 16 + l16) * LDSK + quad * 8];
            bfv[t] = *(const bf16x8*)&Bs[(wc * 64 + t * 16 + l16) * LDSK + quad * 8];
        }
#pragma unroll
        for (int mi = 0; mi < 4; ++mi)
#pragma unroll
            for (int nj = 0; nj < 4; ++nj)
                acc[mi][nj] = MFMA16(af[mi], bfv[nj], acc[mi][nj]);
    }

#pragma unroll
    for (int nj = 0; nj < 4; ++nj) {
        int col = n0 + wc * 64 + nj * 16 + l16;
        float bv = bias[col];
#pragma unroll
        for (int mi = 0; mi < 4; ++mi)
#pragma unroll
            for (int r = 0; r < 4; ++r) {
                int row = m0 + wr * 64 + mi * 16 + quad * 4 + r;
                C[(size_t)row * N + col] = acc[mi][nj][r] + bv;   // F32 store
            }
    }
}

// ---------------------------------------------------------------------------
// Flash attention: grid (L/64, B*H). 4 waves, each wave owns 16 Q rows.
// Q,K: (BH,2048,64) bf16; V^T: (BH,64,2048) bf16; ctx: (B,2048,768) bf16.
// ---------------------------------------------------------------------------
__global__ __launch_bounds__(256) void flash_attn(
    const bf16* __restrict__ Q, const bf16* __restrict__ K,
    const bf16* __restrict__ V, const int* __restrict__ mask,
    bf16* __restrict__ ctx) {
    __shared__ __align__(16) bf16 Ks[64 * 64];      // [key][d]
    __shared__ __align__(16) bf16 Vs[64 * 64];      // [d][key]  (V^T tile)
    __shared__ __align__(16) bf16 Ps[4][16 * 64];   // per-wave P [qrow][key]

    int tid = threadIdx.x, lane = tid & 63, wave = tid >> 6;
    int quad = lane >> 4, l16 = lane & 15;
    int bh = blockIdx.y, b = bh / 12;
    int q0 = blockIdx.x * 64;

    const bf16* Qp = Q + ((size_t)bh * 2048 + q0 + wave * 16 + l16) * 64;
    bf16x8 aq0 = *(const bf16x8*)(Qp + quad * 8);
    bf16x8 aq1 = *(const bf16x8*)(Qp + 32 + quad * 8);

    const f32x4 fz = {0.f, 0.f, 0.f, 0.f};
    f32x4 o[4];
    float m_i[4], l_i[4];
#pragma unroll
    for (int r = 0; r < 4; ++r) { o[r] = fz; m_i[r] = NEG_BIG; l_i[r] = 0.f; }
    const int* mrow = mask + b * 2048;

    for (int kb = 0; kb < 2048; kb += 64) {
#pragma unroll
        for (int i = 0; i < 2; ++i) {
            int idx = tid + i * 256;
            int row = idx >> 3, c8 = (idx & 7) * 8;
            *(bf16x8*)&Ks[row * 64 + c8] =
                *(const bf16x8*)&K[((size_t)bh * 2048 + kb + row) * 64 + c8];
            *(bf16x8*)&Vs[row * 64 + c8] =
                *(const bf16x8*)&V[((size_t)bh * 64 + row) * 2048 + kb + c8];
        }
        __syncthreads();

        f32x4 s[4];
#pragma unroll
        for (int ct = 0; ct < 4; ++ct) {
            const bf16* kp = &Ks[(ct * 16 + l16) * 64 + quad * 8];
            f32x4 t = fz;
            t = MFMA16(aq0, *(const bf16x8*)kp, t);
            t = MFMA16(aq1, *(const bf16x8*)(kp + 32), t);
            s[ct] = t;
        }

        float mx[4] = {NEG_BIG, NEG_BIG, NEG_BIG, NEG_BIG};
#pragma unroll
        for (int ct = 0; ct < 4; ++ct) {
            bool keep = mrow[kb + ct * 16 + l16] != 0;
#pragma unroll
            for (int r = 0; r < 4; ++r) {
                float v = s[ct][r] * 0.125f;
                v = keep ? v : NEG_BIG;
                s[ct][r] = v;
                mx[r] = fmaxf(mx[r], v);
            }
        }
#pragma unroll
        for (int off = 1; off < 16; off <<= 1)
#pragma unroll
            for (int r = 0; r < 4; ++r)
                mx[r] = fmaxf(mx[r], __shfl_xor(mx[r], off));

        float alpha[4], rs[4];
#pragma unroll
        for (int r = 0; r < 4; ++r) {
            float nm = fmaxf(m_i[r], mx[r]);
            alpha[r] = __expf(m_i[r] - nm);
            m_i[r] = nm;
            float sum = 0.f;
#pragma unroll
            for (int ct = 0; ct < 4; ++ct) {
                float p = __expf(s[ct][r] - nm);
                s[ct][r] = p;
                sum += p;
            }
            rs[r] = sum;
        }
#pragma unroll
        for (int off = 1; off < 16; off <<= 1)
#pragma unroll
            for (int r = 0; r < 4; ++r) rs[r] += __shfl_xor(rs[r], off);
#pragma unroll
        for (int r = 0; r < 4; ++r) l_i[r] = l_i[r] * alpha[r] + rs[r];
#pragma unroll
        for (int dt = 0; dt < 4; ++dt)
#pragma unroll
            for (int r = 0; r < 4; ++r) o[dt][r] *= alpha[r];

#pragma unroll
        for (int ct = 0; ct < 4; ++ct)
#pragma unroll
            for (int r = 0; r < 4; ++r)
                Ps[wave][(quad * 4 + r) * 64 + ct * 16 + l16] = (bf16)s[ct][r];
        __syncthreads();

#pragma unroll
        for (int ks = 0; ks < 2; ++ks) {
            bf16x8 ap = *(const bf16x8*)&Ps[wave][l16 * 64 + ks * 32 + quad * 8];
#pragma unroll
            for (int dt = 0; dt < 4; ++dt) {
                bf16x8 bv = *(const bf16x8*)&Vs[(dt * 16 + l16) * 64 + ks * 32 + quad * 8];
                o[dt] = MFMA16(ap, bv, o[dt]);
            }
        }
        __syncthreads();
    }

    int h = bh % 12;
#pragma unroll
    for (int dt = 0; dt < 4; ++dt)
#pragma unroll
        for (int r = 0; r < 4; ++r) {
            int qrow = q0 + wave * 16 + quad * 4 + r;
            float val = o[dt][r] / l_i[r];
            ctx[((size_t)b * 2048 + qrow) * 768 + h * 64 + dt * 16 + l16] = (bf16)val;
        }
}

// ---------------------------------------------------------------------------
extern "C" void kernel_launch(void* const* d_in, const int* in_sizes, int n_in,
                              void* d_out, int out_size, void* d_ws, size_t ws_size,
                              hipStream_t stream) {
    float* out = (float*)d_out;   // OUTPUT IS FLOAT32 (per reference dtype)

    // Size-based input binding (validated round 9: all six sizes matched).
    const float* x = nullptr; const int* mask = nullptr;
    const float* w_qkv = nullptr; const float* b_qkv = nullptr;
    const float* w_out = nullptr; const float* b_out = nullptr;
    int found = 0;
    for (int i = 0; i < n_in; ++i) {
        switch (in_sizes[i]) {
            case 3145728: x     = (const float*)d_in[i]; found |= 1;  break;
            case 4096:    mask  = (const int*)  d_in[i]; found |= 2;  break;
            case 1769472: w_qkv = (const float*)d_in[i]; found |= 4;  break;
            case 2304:    b_qkv = (const float*)d_in[i]; found |= 8;  break;
            case 589824:  w_out = (const float*)d_in[i]; found |= 16; break;
            case 768:     b_out = (const float*)d_in[i]; found |= 32; break;
        }
    }
    if (found != 63) {
        mark_k<<<(out_size + 255) / 256, 256, 0, stream>>>(
            out, 200.0f + (float)found, out_size);
        return;
    }

    const int M = 4096, D = 768, N3 = 2304;
    const size_t HEADS_ELEMS = (size_t)24 * 2048 * 64;  // 3,145,728 elems

    // Workspace layout (23.6 MB; fits per round-6 probe):
    bf16* ws    = (bf16*)d_ws;
    bf16* Kh    = ws;                               // (BH,L,64)   6.29 MB
    bf16* Vth   = Kh + HEADS_ELEMS;                 // (BH,64,L)   6.29 MB
    bf16* ctx   = Vth + HEADS_ELEMS;                // (B,L,768)   6.29 MB
    bf16* wqkvT = ctx + (size_t)M * D;              // 2304x768    3.54 MB
    bf16* woutT = wqkvT + (size_t)N3 * D;           // 768x768     1.18 MB
    bf16* Qh    = (bf16*)d_out;                     // Q parks in d_out (6.3 of
                                                    // 12.6 MB), consumed by
                                                    // flash before out-GEMM.

    transpose_cvt_k<<<(768 * 2304 + 255) / 256, 256, 0, stream>>>(w_qkv, wqkvT, 768, 2304);
    transpose_cvt_k<<<(768 * 768 + 255) / 256, 256, 0, stream>>>(w_out, woutT, 768, 768);

    gemm_qkv_fused<<<dim3(N3 / 128, M / 128), 256, 0, stream>>>(
        x, wqkvT, b_qkv, Qh, Kh, Vth);

    flash_attn<<<dim3(2048 / 64, 24), 256, 0, stream>>>(Qh, Kh, Vth, mask, ctx);

    gemm_out_f32<<<dim3(D / 128, M / 128), 256, 0, stream>>>(
        ctx, woutT, b_out, out, M, D, D);
}

// Round 11
// 247.879 us; speedup vs baseline: 1.1234x; 1.1234x over previous
//
#include <hip/hip_runtime.h>

typedef __bf16 bf16;
typedef bf16 bf16x8 __attribute__((ext_vector_type(8)));
typedef float f32x4 __attribute__((ext_vector_type(4)));

#define MFMA16(A, B, C) __builtin_amdgcn_mfma_f32_16x16x32_bf16(A, B, C, 0, 0, 0)
#define NEG_BIG -30000.0f

// ---------------------------------------------------------------------------
__global__ void mark_k(float* __restrict__ out, float val, int n) {
    int i = blockIdx.x * 256 + threadIdx.x;
    if (i < n) out[i] = val;
}

// ---------------------------------------------------------------------------
// Weight transpose + f32->bf16: dst[c*R + r] = (bf16)src[r*C + c]
// ---------------------------------------------------------------------------
__global__ void transpose_cvt_k(const float* __restrict__ src, bf16* __restrict__ dst,
                                int R, int C) {
    int i = blockIdx.x * 256 + threadIdx.x;
    if (i >= R * C) return;
    int r = i / C, c = i % C;
    dst[(size_t)c * R + r] = (bf16)src[i];
}

#define LDSK 40  // padded LDS leading dim (32 + 8), 16B-aligned rows

// ---------------------------------------------------------------------------
// QKV GEMM: A = x (f32), B = wqkvT (bf16, N x K), bias f32.
// Fused head-reshape epilogue; Q pre-scaled by 0.125 (exact: exponent shift).
// ---------------------------------------------------------------------------
__global__ __launch_bounds__(256) void gemm_qkv_fused(
    const float* __restrict__ A, const bf16* __restrict__ B,
    const float* __restrict__ bias, bf16* __restrict__ Qh,
    bf16* __restrict__ Kh, bf16* __restrict__ Vth) {
    __shared__ __align__(16) bf16 As[128 * LDSK];
    __shared__ __align__(16) bf16 Bs[128 * LDSK];

    int tid = threadIdx.x, lane = tid & 63, wave = tid >> 6;
    int quad = lane >> 4, l16 = lane & 15;
    int wr = wave >> 1, wc = wave & 1;
    int m0 = blockIdx.y * 128, n0 = blockIdx.x * 128;
    const int K = 768;

    const f32x4 fz = {0.f, 0.f, 0.f, 0.f};
    f32x4 acc[4][4];
#pragma unroll
    for (int mi = 0; mi < 4; ++mi)
#pragma unroll
        for (int nj = 0; nj < 4; ++nj) acc[mi][nj] = fz;

    const float* Ablk = A + (size_t)m0 * K;
    const bf16*  Bblk = B + (size_t)n0 * K;
    int lrow = tid >> 2;
    int lkc  = (tid & 3) * 8;

    for (int k0 = 0; k0 < K; k0 += 32) {
        __syncthreads();
#pragma unroll
        for (int i = 0; i < 2; ++i) {
            int row = lrow + i * 64;
            const float* ap = &Ablk[(size_t)row * K + k0 + lkc];
            float4 v0 = *(const float4*)ap;
            float4 v1 = *(const float4*)(ap + 4);
            bf16x8 w;
            w[0] = (bf16)v0.x; w[1] = (bf16)v0.y; w[2] = (bf16)v0.z; w[3] = (bf16)v0.w;
            w[4] = (bf16)v1.x; w[5] = (bf16)v1.y; w[6] = (bf16)v1.z; w[7] = (bf16)v1.w;
            *(bf16x8*)&As[row * LDSK + lkc] = w;
            *(bf16x8*)&Bs[row * LDSK + lkc] =
                *(const bf16x8*)&Bblk[(size_t)row * K + k0 + lkc];
        }
        __syncthreads();

        bf16x8 af[4], bfv[4];
#pragma unroll
        for (int t = 0; t < 4; ++t) {
            af[t]  = *(const bf16x8*)&As[(wr * 64 + t * 16 + l16) * LDSK + quad * 8];
            bfv[t] = *(const bf16x8*)&Bs[(wc * 64 + t * 16 + l16) * LDSK + quad * 8];
        }
#pragma unroll
        for (int mi = 0; mi < 4; ++mi)
#pragma unroll
            for (int nj = 0; nj < 4; ++nj)
                acc[mi][nj] = MFMA16(af[mi], bfv[nj], acc[mi][nj]);
    }

#pragma unroll
    for (int nj = 0; nj < 4; ++nj) {
        int col = n0 + wc * 64 + nj * 16 + l16;
        float bv = bias[col];
        int which = col / 768;
        int rr = col % 768;
        int h = rr >> 6, d = rr & 63;
        float scale = (which == 0) ? 0.125f : 1.0f;  // bake QK scale into Q
#pragma unroll
        for (int mi = 0; mi < 4; ++mi)
#pragma unroll
            for (int r = 0; r < 4; ++r) {
                int row = m0 + wr * 64 + mi * 16 + quad * 4 + r;
                int b = row >> 11, l = row & 2047;
                size_t bh = (size_t)(b * 12 + h);
                bf16 val = (bf16)((acc[mi][nj][r] + bv) * scale);
                if (which == 0)      Qh[(bh * 2048 + l) * 64 + d] = val;
                else if (which == 1) Kh[(bh * 2048 + l) * 64 + d] = val;
                else                 Vth[(bh * 64 + d) * 2048 + l] = val;
            }
    }
}

// ---------------------------------------------------------------------------
// Out-projection GEMM: out(F32) = ctx (bf16) @ woutT^T + b_out (f32).
// ---------------------------------------------------------------------------
__global__ __launch_bounds__(256) void gemm_out_f32(
    const bf16* __restrict__ A, const bf16* __restrict__ B,
    const float* __restrict__ bias, float* __restrict__ C,
    int M, int N, int K) {
    __shared__ __align__(16) bf16 As[128 * LDSK];
    __shared__ __align__(16) bf16 Bs[128 * LDSK];

    int tid = threadIdx.x, lane = tid & 63, wave = tid >> 6;
    int quad = lane >> 4, l16 = lane & 15;
    int wr = wave >> 1, wc = wave & 1;
    int m0 = blockIdx.y * 128, n0 = blockIdx.x * 128;

    const f32x4 fz = {0.f, 0.f, 0.f, 0.f};
    f32x4 acc[4][4];
#pragma unroll
    for (int mi = 0; mi < 4; ++mi)
#pragma unroll
        for (int nj = 0; nj < 4; ++nj) acc[mi][nj] = fz;

    const bf16* Ablk = A + (size_t)m0 * K;
    const bf16* Bblk = B + (size_t)n0 * K;
    int lrow = tid >> 2;
    int lkc  = (tid & 3) * 8;

    for (int k0 = 0; k0 < K; k0 += 32) {
        __syncthreads();
#pragma unroll
        for (int i = 0; i < 2; ++i) {
            int row = lrow + i * 64;
            *(bf16x8*)&As[row * LDSK + lkc] =
                *(const bf16x8*)&Ablk[(size_t)row * K + k0 + lkc];
            *(bf16x8*)&Bs[row * LDSK + lkc] =
                *(const bf16x8*)&Bblk[(size_t)row * K + k0 + lkc];
        }
        __syncthreads();

        bf16x8 af[4], bfv[4];
#pragma unroll
        for (int t = 0; t < 4; ++t) {
            af[t]  = *(const bf16x8*)&As[(wr * 64 + t * 16 + l16) * LDSK + quad * 8];
            bfv[t] = *(const bf16x8*)&Bs[(wc * 64 + t * 16 + l16) * LDSK + quad * 8];
        }
#pragma unroll
        for (int mi = 0; mi < 4; ++mi)
#pragma unroll
            for (int nj = 0; nj < 4; ++nj)
                acc[mi][nj] = MFMA16(af[mi], bfv[nj], acc[mi][nj]);
    }

#pragma unroll
    for (int nj = 0; nj < 4; ++nj) {
        int col = n0 + wc * 64 + nj * 16 + l16;
        float bv = bias[col];
#pragma unroll
        for (int mi = 0; mi < 4; ++mi)
#pragma unroll
            for (int r = 0; r < 4; ++r) {
                int row = m0 + wr * 64 + mi * 16 + quad * 4 + r;
                C[(size_t)row * N + col] = acc[mi][nj][r] + bv;
            }
    }
}

// ---------------------------------------------------------------------------
// Flash attention v2: LDS rows padded to 72 elems (kills the 128B-row bank
// aliasing: 2.4e7 conflict cycles in v1), double-buffered K/V tiles (1
// barrier/iter instead of 2; Ps is per-wave so intra-wave lgkmcnt ordering
// suffices). Q arrives pre-scaled by 0.125.
// ---------------------------------------------------------------------------
#define LDR 72  // padded row: 72 bf16 = 144 B (16B-aligned, not 128B-periodic)

__global__ __launch_bounds__(256) void flash_attn(
    const bf16* __restrict__ Q, const bf16* __restrict__ K,
    const bf16* __restrict__ V, const int* __restrict__ mask,
    bf16* __restrict__ ctx) {
    __shared__ __align__(16) bf16 Ks[2][64 * LDR];   // [buf][key][d]
    __shared__ __align__(16) bf16 Vs[2][64 * LDR];   // [buf][d][key]
    __shared__ __align__(16) bf16 Ps[4][16 * LDR];   // per-wave P [qrow][key]

    int tid = threadIdx.x, lane = tid & 63, wave = tid >> 6;
    int quad = lane >> 4, l16 = lane & 15;
    int bh = blockIdx.y, b = bh / 12;
    int q0 = blockIdx.x * 64;

    const bf16* Qp = Q + ((size_t)bh * 2048 + q0 + wave * 16 + l16) * 64;
    bf16x8 aq0 = *(const bf16x8*)(Qp + quad * 8);
    bf16x8 aq1 = *(const bf16x8*)(Qp + 32 + quad * 8);

    const f32x4 fz = {0.f, 0.f, 0.f, 0.f};
    f32x4 o[4];
    float m_i[4], l_i[4];
#pragma unroll
    for (int r = 0; r < 4; ++r) { o[r] = fz; m_i[r] = NEG_BIG; l_i[r] = 0.f; }
    const int* mrow = mask + b * 2048;

    int srow = tid >> 3;            // 0..31 staging row (x2 halves)
    int sc8  = (tid & 7) * 8;       // column chunk
    const bf16* Kbase = K + (size_t)bh * 2048 * 64;
    const bf16* Vbase = V + (size_t)bh * 64 * 2048;

    // Prologue: stage tile 0 into buffer 0
#pragma unroll
    for (int i = 0; i < 2; ++i) {
        int row = srow + i * 32;
        *(bf16x8*)&Ks[0][row * LDR + sc8] =
            *(const bf16x8*)&Kbase[(size_t)row * 64 + sc8];
        *(bf16x8*)&Vs[0][row * LDR + sc8] =
            *(const bf16x8*)&Vbase[(size_t)row * 2048 + sc8];
    }

    int p = 0;
    for (int kb = 0; kb < 2048; kb += 64) {
        __syncthreads();   // buf p staged; all waves done with buf p's prior use

        if (kb + 64 < 2048) {   // stage next tile into buf 1-p (overlaps compute)
            int nb = kb + 64;
#pragma unroll
            for (int i = 0; i < 2; ++i) {
                int row = srow + i * 32;
                *(bf16x8*)&Ks[1 - p][row * LDR + sc8] =
                    *(const bf16x8*)&Kbase[(size_t)(nb + row) * 64 + sc8];
                *(bf16x8*)&Vs[1 - p][row * LDR + sc8] =
                    *(const bf16x8*)&Vbase[(size_t)row * 2048 + nb + sc8];
            }
        }

        // S = Q K^T (Q pre-scaled)
        f32x4 s[4];
#pragma unroll
        for (int ct = 0; ct < 4; ++ct) {
            const bf16* kp = &Ks[p][(ct * 16 + l16) * LDR + quad * 8];
            f32x4 t = fz;
            t = MFMA16(aq0, *(const bf16x8*)kp, t);
            t = MFMA16(aq1, *(const bf16x8*)(kp + 32), t);
            s[ct] = t;
        }

        // mask + row-max
        float mx[4] = {NEG_BIG, NEG_BIG, NEG_BIG, NEG_BIG};
#pragma unroll
        for (int ct = 0; ct < 4; ++ct) {
            bool keep = mrow[kb + ct * 16 + l16] != 0;
#pragma unroll
            for (int r = 0; r < 4; ++r) {
                float v = keep ? s[ct][r] : NEG_BIG;
                s[ct][r] = v;
                mx[r] = fmaxf(mx[r], v);
            }
        }
#pragma unroll
        for (int off = 1; off < 16; off <<= 1)
#pragma unroll
            for (int r = 0; r < 4; ++r)
                mx[r] = fmaxf(mx[r], __shfl_xor(mx[r], off));

        float alpha[4], rs[4];
#pragma unroll
        for (int r = 0; r < 4; ++r) {
            float nm = fmaxf(m_i[r], mx[r]);
            alpha[r] = __expf(m_i[r] - nm);
            m_i[r] = nm;
            float sum = 0.f;
#pragma unroll
            for (int ct = 0; ct < 4; ++ct) {
                float pv = __expf(s[ct][r] - nm);
                s[ct][r] = pv;
                sum += pv;
            }
            rs[r] = sum;
        }
#pragma unroll
        for (int off = 1; off < 16; off <<= 1)
#pragma unroll
            for (int r = 0; r < 4; ++r) rs[r] += __shfl_xor(rs[r], off);
#pragma unroll
        for (int r = 0; r < 4; ++r) l_i[r] = l_i[r] * alpha[r] + rs[r];
#pragma unroll
        for (int dt = 0; dt < 4; ++dt)
#pragma unroll
            for (int r = 0; r < 4; ++r) o[dt][r] *= alpha[r];

        // P: C-layout -> per-wave LDS (row-major) -> A-layout reload.
        // Same-wave producer/consumer: hardware lgkmcnt ordering, no barrier.
#pragma unroll
        for (int ct = 0; ct < 4; ++ct)
#pragma unroll
            for (int r = 0; r < 4; ++r)
                Ps[wave][(quad * 4 + r) * LDR + ct * 16 + l16] = (bf16)s[ct][r];

#pragma unroll
        for (int ks = 0; ks < 2; ++ks) {
            bf16x8 ap = *(const bf16x8*)&Ps[wave][l16 * LDR + ks * 32 + quad * 8];
#pragma unroll
            for (int dt = 0; dt < 4; ++dt) {
                bf16x8 bv = *(const bf16x8*)&Vs[p][(dt * 16 + l16) * LDR + ks * 32 + quad * 8];
                o[dt] = MFMA16(ap, bv, o[dt]);
            }
        }
        p ^= 1;
    }

    int h = bh % 12;
#pragma unroll
    for (int dt = 0; dt < 4; ++dt)
#pragma unroll
        for (int r = 0; r < 4; ++r) {
            int qrow = q0 + wave * 16 + quad * 4 + r;
            float val = o[dt][r] / l_i[r];
            ctx[((size_t)b * 2048 + qrow) * 768 + h * 64 + dt * 16 + l16] = (bf16)val;
        }
}

// ---------------------------------------------------------------------------
extern "C" void kernel_launch(void* const* d_in, const int* in_sizes, int n_in,
                              void* d_out, int out_size, void* d_ws, size_t ws_size,
                              hipStream_t stream) {
    float* out = (float*)d_out;   // f32 output (validated round 10)

    const float* x = nullptr; const int* mask = nullptr;
    const float* w_qkv = nullptr; const float* b_qkv = nullptr;
    const float* w_out = nullptr; const float* b_out = nullptr;
    int found = 0;
    for (int i = 0; i < n_in; ++i) {
        switch (in_sizes[i]) {
            case 3145728: x     = (const float*)d_in[i]; found |= 1;  break;
            case 4096:    mask  = (const int*)  d_in[i]; found |= 2;  break;
            case 1769472: w_qkv = (const float*)d_in[i]; found |= 4;  break;
            case 2304:    b_qkv = (const float*)d_in[i]; found |= 8;  break;
            case 589824:  w_out = (const float*)d_in[i]; found |= 16; break;
            case 768:     b_out = (const float*)d_in[i]; found |= 32; break;
        }
    }
    if (found != 63) {
        mark_k<<<(out_size + 255) / 256, 256, 0, stream>>>(
            out, 200.0f + (float)found, out_size);
        return;
    }

    const int M = 4096, D = 768, N3 = 2304;
    const size_t HEADS_ELEMS = (size_t)24 * 2048 * 64;

    bf16* ws    = (bf16*)d_ws;
    bf16* Kh    = ws;
    bf16* Vth   = Kh + HEADS_ELEMS;
    bf16* ctx   = Vth + HEADS_ELEMS;
    bf16* wqkvT = ctx + (size_t)M * D;
    bf16* woutT = wqkvT + (size_t)N3 * D;
    bf16* Qh    = (bf16*)d_out;    // Q parks in d_out, consumed before out-GEMM

    transpose_cvt_k<<<(768 * 2304 + 255) / 256, 256, 0, stream>>>(w_qkv, wqkvT, 768, 2304);
    transpose_cvt_k<<<(768 * 768 + 255) / 256, 256, 0, stream>>>(w_out, woutT, 768, 768);

    gemm_qkv_fused<<<dim3(N3 / 128, M / 128), 256, 0, stream>>>(
        x, wqkvT, b_qkv, Qh, Kh, Vth);

    flash_attn<<<dim3(2048 / 64, 24), 256, 0, stream>>>(Qh, Kh, Vth, mask, ctx);

    gemm_out_f32<<<dim3(D / 128, M / 128), 256, 0, stream>>>(
        ctx, woutT, b_out, out, M, D, D);
}

// Round 12
// 221.567 us; speedup vs baseline: 1.2568x; 1.1188x over previous
//
#include <hip/hip_runtime.h>

typedef __bf16 bf16;
typedef bf16 bf16x4 __attribute__((ext_vector_type(4)));
typedef bf16 bf16x8 __attribute__((ext_vector_type(8)));
typedef float f32x4 __attribute__((ext_vector_type(4)));

#define MFMA16(A, B, C) __builtin_amdgcn_mfma_f32_16x16x32_bf16(A, B, C, 0, 0, 0)
#define NEG_BIG -30000.0f

// ---------------------------------------------------------------------------
__global__ void mark_k(float* __restrict__ out, float val, int n) {
    int i = blockIdx.x * 256 + threadIdx.x;
    if (i < n) out[i] = val;
}

// ---------------------------------------------------------------------------
// LDS-tiled transpose + f32->bf16: dst[c*R + r] = (bf16)src[r*C + c].
// Grid (C/32, R/32), 256 threads. Coalesced read AND write.
// ---------------------------------------------------------------------------
__global__ __launch_bounds__(256) void transpose_cvt_tiled(
    const float* __restrict__ src, bf16* __restrict__ dst, int R, int C) {
    __shared__ float t[32][33];
    int tid = threadIdx.x, tx = tid & 31, ty = tid >> 5;  // ty 0..7
    int bx = blockIdx.x * 32, by = blockIdx.y * 32;
#pragma unroll
    for (int i = 0; i < 4; ++i) {
        int row = by + ty + i * 8;
        t[ty + i * 8][tx] = src[(size_t)row * C + bx + tx];
    }
    __syncthreads();
#pragma unroll
    for (int i = 0; i < 4; ++i) {
        int outrow = bx + ty + i * 8;          // transposed row = src col
        dst[(size_t)outrow * R + by + tx] = (bf16)t[tx][ty + i * 8];
    }
}

#define LDSK 40  // padded LDS leading dim for GEMMs (32 + 8)

// ---------------------------------------------------------------------------
// QKV GEMM: A = x (f32), B = wqkvT (bf16, N x K), bias f32.
// Fused head-reshape epilogue; Q pre-scaled by 0.125 (exact: exponent shift).
// ---------------------------------------------------------------------------
__global__ __launch_bounds__(256) void gemm_qkv_fused(
    const float* __restrict__ A, const bf16* __restrict__ B,
    const float* __restrict__ bias, bf16* __restrict__ Qh,
    bf16* __restrict__ Kh, bf16* __restrict__ Vth) {
    __shared__ __align__(16) bf16 As[128 * LDSK];
    __shared__ __align__(16) bf16 Bs[128 * LDSK];

    int tid = threadIdx.x, lane = tid & 63, wave = tid >> 6;
    int quad = lane >> 4, l16 = lane & 15;
    int wr = wave >> 1, wc = wave & 1;
    int m0 = blockIdx.y * 128, n0 = blockIdx.x * 128;
    const int K = 768;

    const f32x4 fz = {0.f, 0.f, 0.f, 0.f};
    f32x4 acc[4][4];
#pragma unroll
    for (int mi = 0; mi < 4; ++mi)
#pragma unroll
        for (int nj = 0; nj < 4; ++nj) acc[mi][nj] = fz;

    const float* Ablk = A + (size_t)m0 * K;
    const bf16*  Bblk = B + (size_t)n0 * K;
    int lrow = tid >> 2;
    int lkc  = (tid & 3) * 8;

    for (int k0 = 0; k0 < K; k0 += 32) {
        __syncthreads();
#pragma unroll
        for (int i = 0; i < 2; ++i) {
            int row = lrow + i * 64;
            const float* ap = &Ablk[(size_t)row * K + k0 + lkc];
            float4 v0 = *(const float4*)ap;
            float4 v1 = *(const float4*)(ap + 4);
            bf16x8 w;
            w[0] = (bf16)v0.x; w[1] = (bf16)v0.y; w[2] = (bf16)v0.z; w[3] = (bf16)v0.w;
            w[4] = (bf16)v1.x; w[5] = (bf16)v1.y; w[6] = (bf16)v1.z; w[7] = (bf16)v1.w;
            *(bf16x8*)&As[row * LDSK + lkc] = w;
            *(bf16x8*)&Bs[row * LDSK + lkc] =
                *(const bf16x8*)&Bblk[(size_t)row * K + k0 + lkc];
        }
        __syncthreads();

        bf16x8 af[4], bfv[4];
#pragma unroll
        for (int t = 0; t < 4; ++t) {
            af[t]  = *(const bf16x8*)&As[(wr * 64 + t * 16 + l16) * LDSK + quad * 8];
            bfv[t] = *(const bf16x8*)&Bs[(wc * 64 + t * 16 + l16) * LDSK + quad * 8];
        }
#pragma unroll
        for (int mi = 0; mi < 4; ++mi)
#pragma unroll
            for (int nj = 0; nj < 4; ++nj)
                acc[mi][nj] = MFMA16(af[mi], bfv[nj], acc[mi][nj]);
    }

#pragma unroll
    for (int nj = 0; nj < 4; ++nj) {
        int col = n0 + wc * 64 + nj * 16 + l16;
        float bv = bias[col];
        int which = col / 768;
        int rr = col % 768;
        int h = rr >> 6, d = rr & 63;
        float scale = (which == 0) ? 0.125f : 1.0f;
#pragma unroll
        for (int mi = 0; mi < 4; ++mi)
#pragma unroll
            for (int r = 0; r < 4; ++r) {
                int row = m0 + wr * 64 + mi * 16 + quad * 4 + r;
                int b = row >> 11, l = row & 2047;
                size_t bh = (size_t)(b * 12 + h);
                bf16 val = (bf16)((acc[mi][nj][r] + bv) * scale);
                if (which == 0)      Qh[(bh * 2048 + l) * 64 + d] = val;
                else if (which == 1) Kh[(bh * 2048 + l) * 64 + d] = val;
                else                 Vth[(bh * 64 + d) * 2048 + l] = val;
            }
    }
}

// ---------------------------------------------------------------------------
// Out-projection GEMM: out(F32) = ctx (bf16) @ woutT^T + b_out (f32).
// ---------------------------------------------------------------------------
__global__ __launch_bounds__(256) void gemm_out_f32(
    const bf16* __restrict__ A, const bf16* __restrict__ B,
    const float* __restrict__ bias, float* __restrict__ C,
    int M, int N, int K) {
    __shared__ __align__(16) bf16 As[128 * LDSK];
    __shared__ __align__(16) bf16 Bs[128 * LDSK];

    int tid = threadIdx.x, lane = tid & 63, wave = tid >> 6;
    int quad = lane >> 4, l16 = lane & 15;
    int wr = wave >> 1, wc = wave & 1;
    int m0 = blockIdx.y * 128, n0 = blockIdx.x * 128;

    const f32x4 fz = {0.f, 0.f, 0.f, 0.f};
    f32x4 acc[4][4];
#pragma unroll
    for (int mi = 0; mi < 4; ++mi)
#pragma unroll
        for (int nj = 0; nj < 4; ++nj) acc[mi][nj] = fz;

    const bf16* Ablk = A + (size_t)m0 * K;
    const bf16* Bblk = B + (size_t)n0 * K;
    int lrow = tid >> 2;
    int lkc  = (tid & 3) * 8;

    for (int k0 = 0; k0 < K; k0 += 32) {
        __syncthreads();
#pragma unroll
        for (int i = 0; i < 2; ++i) {
            int row = lrow + i * 64;
            *(bf16x8*)&As[row * LDSK + lkc] =
                *(const bf16x8*)&Ablk[(size_t)row * K + k0 + lkc];
            *(bf16x8*)&Bs[row * LDSK + lkc] =
                *(const bf16x8*)&Bblk[(size_t)row * K + k0 + lkc];
        }
        __syncthreads();

        bf16x8 af[4], bfv[4];
#pragma unroll
        for (int t = 0; t < 4; ++t) {
            af[t]  = *(const bf16x8*)&As[(wr * 64 + t * 16 + l16) * LDSK + quad * 8];
            bfv[t] = *(const bf16x8*)&Bs[(wc * 64 + t * 16 + l16) * LDSK + quad * 8];
        }
#pragma unroll
        for (int mi = 0; mi < 4; ++mi)
#pragma unroll
            for (int nj = 0; nj < 4; ++nj)
                acc[mi][nj] = MFMA16(af[mi], bfv[nj], acc[mi][nj]);
    }

#pragma unroll
    for (int nj = 0; nj < 4; ++nj) {
        int col = n0 + wc * 64 + nj * 16 + l16;
        float bv = bias[col];
#pragma unroll
        for (int mi = 0; mi < 4; ++mi)
#pragma unroll
            for (int r = 0; r < 4; ++r) {
                int row = m0 + wr * 64 + mi * 16 + quad * 4 + r;
                C[(size_t)row * N + col] = acc[mi][nj][r] + bv;
            }
    }
}

// ---------------------------------------------------------------------------
// Flash attention v3:
//  * S^T via swapped MFMA operands (A=K, B=Q): softmax state scalar per lane
//    (qrow = l16), P stored with ds_write_b64 (4 consecutive keys per lane).
//  * 2 qrow-tiles per wave (32 qrows): K/V LDS fragments shared across both.
//  * XOR-swizzled K/V tiles (LDR 64, chunk^=row&7): kills residual bank alias.
//  * Additive f32 mask staged once per block in LDS.
//  * Double-buffered K/V, 1 barrier/iter. 128 threads, grid (32, 24).
// ---------------------------------------------------------------------------
#define SW(r, c8) ((r) * 64 + (((((c8) >> 3) ^ ((r) & 7))) << 3))
#define PLD 72   // Ps leading dim (pad keeps b64 writes 2-way max)

__global__ __launch_bounds__(128) void flash_attn(
    const bf16* __restrict__ Q, const bf16* __restrict__ K,
    const bf16* __restrict__ V, const int* __restrict__ mask,
    bf16* __restrict__ ctx) {
    __shared__ __align__(16) bf16 Ks[2][64 * 64];
    __shared__ __align__(16) bf16 Vs[2][64 * 64];
    __shared__ __align__(16) bf16 Ps[2][16 * PLD];   // per-wave
    __shared__ float maskS[2048];

    int tid = threadIdx.x, lane = tid & 63, wave = tid >> 6;  // wave 0..1
    int quad = lane >> 4, l16 = lane & 15;
    int bh = blockIdx.y, b = bh / 12;
    int q0 = blockIdx.x * 64 + wave * 32;

    // Q fragments (B-operand layout = A layout): two 16-row tiles
    bf16x8 aq[2][2];
#pragma unroll
    for (int qt = 0; qt < 2; ++qt) {
        const bf16* Qp = Q + ((size_t)bh * 2048 + q0 + qt * 16 + l16) * 64;
        aq[qt][0] = *(const bf16x8*)(Qp + quad * 8);
        aq[qt][1] = *(const bf16x8*)(Qp + 32 + quad * 8);
    }

    // Stage additive mask (f32) once
    const int* mrow = mask + b * 2048;
#pragma unroll
    for (int i = 0; i < 16; ++i) {
        int idx = i * 128 + tid;
        maskS[idx] = (mrow[idx] != 0) ? 0.0f : NEG_BIG;
    }

    const f32x4 fz = {0.f, 0.f, 0.f, 0.f};
    f32x4 o[2][4];
    float m_i[2], l_i[2];
#pragma unroll
    for (int qt = 0; qt < 2; ++qt) {
        m_i[qt] = NEG_BIG; l_i[qt] = 0.f;
#pragma unroll
        for (int dt = 0; dt < 4; ++dt) o[qt][dt] = fz;
    }

    int srow = tid >> 3;            // 0..15
    int sc8  = (tid & 7) * 8;
    const bf16* Kbase = K + (size_t)bh * 2048 * 64;
    const bf16* Vbase = V + (size_t)bh * 64 * 2048;

    // Prologue: stage tile 0 into buffer 0 (swizzled)
#pragma unroll
    for (int i = 0; i < 4; ++i) {
        int row = srow + i * 16;
        *(bf16x8*)&Ks[0][SW(row, sc8)] =
            *(const bf16x8*)&Kbase[(size_t)row * 64 + sc8];
        *(bf16x8*)&Vs[0][SW(row, sc8)] =
            *(const bf16x8*)&Vbase[(size_t)row * 2048 + sc8];
    }

    int p = 0;
    for (int kb = 0; kb < 2048; kb += 64) {
        __syncthreads();

        if (kb + 64 < 2048) {
            int nb = kb + 64;
#pragma unroll
            for (int i = 0; i < 4; ++i) {
                int row = srow + i * 16;
                *(bf16x8*)&Ks[1 - p][SW(row, sc8)] =
                    *(const bf16x8*)&Kbase[(size_t)(nb + row) * 64 + sc8];
                *(bf16x8*)&Vs[1 - p][SW(row, sc8)] =
                    *(const bf16x8*)&Vbase[(size_t)row * 2048 + nb + sc8];
            }
        }

        // S^T = K Q^T : lane holds key = ct*16 + quad*4 + r, qrow = l16
        f32x4 s[2][4];
#pragma unroll
        for (int ct = 0; ct < 4; ++ct) {
            int krow = ct * 16 + l16;
            bf16x8 kf0 = *(const bf16x8*)&Ks[p][SW(krow, quad * 8)];
            bf16x8 kf1 = *(const bf16x8*)&Ks[p][SW(krow, 32 + quad * 8)];
#pragma unroll
            for (int qt = 0; qt < 2; ++qt) {
                f32x4 t = fz;
                t = MFMA16(kf0, aq[qt][0], t);
                t = MFMA16(kf1, aq[qt][1], t);
                s[qt][ct] = t;
            }
        }

        // additive mask (same for both qt)
#pragma unroll
        for (int ct = 0; ct < 4; ++ct) {
            const float* mk = &maskS[kb + ct * 16 + quad * 4];
            float4 mv = *(const float4*)mk;
            float ma[4] = {mv.x, mv.y, mv.z, mv.w};
#pragma unroll
            for (int qt = 0; qt < 2; ++qt)
#pragma unroll
                for (int r = 0; r < 4; ++r) s[qt][ct][r] += ma[r];
        }

        // online softmax per qt (state scalar per lane, qrow = l16)
        float alpha[2];
#pragma unroll
        for (int qt = 0; qt < 2; ++qt) {
            float mx = NEG_BIG;
#pragma unroll
            for (int ct = 0; ct < 4; ++ct)
#pragma unroll
                for (int r = 0; r < 4; ++r) mx = fmaxf(mx, s[qt][ct][r]);
            mx = fmaxf(mx, __shfl_xor(mx, 16));
            mx = fmaxf(mx, __shfl_xor(mx, 32));
            float nm = fmaxf(m_i[qt], mx);
            alpha[qt] = __expf(m_i[qt] - nm);
            m_i[qt] = nm;
            float sum = 0.f;
#pragma unroll
            for (int ct = 0; ct < 4; ++ct)
#pragma unroll
                for (int r = 0; r < 4; ++r) {
                    float pv = __expf(s[qt][ct][r] - nm);
                    s[qt][ct][r] = pv;
                    sum += pv;
                }
            sum += __shfl_xor(sum, 16);
            sum += __shfl_xor(sum, 32);
            l_i[qt] = l_i[qt] * alpha[qt] + sum;
        }

        // rescale o: needs alpha at qrow = quad*4 + r (lives at lane l16=q)
#pragma unroll
        for (int qt = 0; qt < 2; ++qt) {
            float ab[4];
#pragma unroll
            for (int r = 0; r < 4; ++r)
                ab[r] = __shfl(alpha[qt], (lane & 48) | (quad * 4 + r));
#pragma unroll
            for (int dt = 0; dt < 4; ++dt)
#pragma unroll
                for (int r = 0; r < 4; ++r) o[qt][dt][r] *= ab[r];
        }

        // V fragments (shared across qt): B[n=d][k=key]
        bf16x8 vf[2][4];
#pragma unroll
        for (int ks = 0; ks < 2; ++ks)
#pragma unroll
            for (int dt = 0; dt < 4; ++dt)
                vf[ks][dt] = *(const bf16x8*)&Vs[p][SW(dt * 16 + l16, ks * 32 + quad * 8)];

        // P round-trip + PV per qt (same-wave DS ordering: no barrier)
#pragma unroll
        for (int qt = 0; qt < 2; ++qt) {
#pragma unroll
            for (int ct = 0; ct < 4; ++ct) {
                bf16x4 pk;
#pragma unroll
                for (int r = 0; r < 4; ++r) pk[r] = (bf16)s[qt][ct][r];
                *(bf16x4*)&Ps[wave][l16 * PLD + ct * 16 + quad * 4] = pk;
            }
#pragma unroll
            for (int ks = 0; ks < 2; ++ks) {
                bf16x8 ap = *(const bf16x8*)&Ps[wave][l16 * PLD + ks * 32 + quad * 8];
#pragma unroll
                for (int dt = 0; dt < 4; ++dt)
                    o[qt][dt] = MFMA16(ap, vf[ks][dt], o[qt][dt]);
            }
        }
        p ^= 1;
    }

    // epilogue: ctx[b][qrow][h*64 + d]; l_i lives at lane l16 = qrow-local
    int h = bh % 12;
#pragma unroll
    for (int qt = 0; qt < 2; ++qt) {
        float linv[4];
#pragma unroll
        for (int r = 0; r < 4; ++r)
            linv[r] = 1.0f / __shfl(l_i[qt], (lane & 48) | (quad * 4 + r));
#pragma unroll
        for (int dt = 0; dt < 4; ++dt)
#pragma unroll
            for (int r = 0; r < 4; ++r) {
                int qrow = q0 + qt * 16 + quad * 4 + r;
                ctx[((size_t)b * 2048 + qrow) * 768 + h * 64 + dt * 16 + l16] =
                    (bf16)(o[qt][dt][r] * linv[r]);
            }
    }
}

// ---------------------------------------------------------------------------
extern "C" void kernel_launch(void* const* d_in, const int* in_sizes, int n_in,
                              void* d_out, int out_size, void* d_ws, size_t ws_size,
                              hipStream_t stream) {
    float* out = (float*)d_out;   // f32 output (validated round 10)

    const float* x = nullptr; const int* mask = nullptr;
    const float* w_qkv = nullptr; const float* b_qkv = nullptr;
    const float* w_out = nullptr; const float* b_out = nullptr;
    int found = 0;
    for (int i = 0; i < n_in; ++i) {
        switch (in_sizes[i]) {
            case 3145728: x     = (const float*)d_in[i]; found |= 1;  break;
            case 4096:    mask  = (const int*)  d_in[i]; found |= 2;  break;
            case 1769472: w_qkv = (const float*)d_in[i]; found |= 4;  break;
            case 2304:    b_qkv = (const float*)d_in[i]; found |= 8;  break;
            case 589824:  w_out = (const float*)d_in[i]; found |= 16; break;
            case 768:     b_out = (const float*)d_in[i]; found |= 32; break;
        }
    }
    if (found != 63) {
        mark_k<<<(out_size + 255) / 256, 256, 0, stream>>>(
            out, 200.0f + (float)found, out_size);
        return;
    }

    const int M = 4096, D = 768, N3 = 2304;
    const size_t HEADS_ELEMS = (size_t)24 * 2048 * 64;

    bf16* ws    = (bf16*)d_ws;
    bf16* Kh    = ws;
    bf16* Vth   = Kh + HEADS_ELEMS;
    bf16* ctx   = Vth + HEADS_ELEMS;
    bf16* wqkvT = ctx + (size_t)M * D;
    bf16* woutT = wqkvT + (size_t)N3 * D;
    bf16* Qh    = (bf16*)d_out;    // Q parks in d_out, consumed before out-GEMM

    transpose_cvt_tiled<<<dim3(2304 / 32, 768 / 32), 256, 0, stream>>>(
        w_qkv, wqkvT, 768, 2304);
    transpose_cvt_tiled<<<dim3(768 / 32, 768 / 32), 256, 0, stream>>>(
        w_out, woutT, 768, 768);

    gemm_qkv_fused<<<dim3(N3 / 128, M / 128), 256, 0, stream>>>(
        x, wqkvT, b_qkv, Qh, Kh, Vth);

    flash_attn<<<dim3(2048 / 64, 24), 128, 0, stream>>>(Qh, Kh, Vth, mask, ctx);

    gemm_out_f32<<<dim3(D / 128, M / 128), 256, 0, stream>>>(
        ctx, woutT, b_out, out, M, D, D);
}

// Round 13
// 213.346 us; speedup vs baseline: 1.3052x; 1.0385x over previous
//
#include <hip/hip_runtime.h>

typedef __bf16 bf16;
typedef bf16 bf16x4 __attribute__((ext_vector_type(4)));
typedef bf16 bf16x8 __attribute__((ext_vector_type(8)));
typedef float f32x4 __attribute__((ext_vector_type(4)));

#define MFMA16(A, B, C) __builtin_amdgcn_mfma_f32_16x16x32_bf16(A, B, C, 0, 0, 0)
#define NEG_BIG -30000.0f

// async 16B global->LDS (m97 pattern): lds dest = wave-uniform base + lane*16
#define GLOAD_LDS16(gptr, lptr)                                                \
    __builtin_amdgcn_global_load_lds(                                          \
        (__attribute__((address_space(1))) void*)(gptr),                       \
        (__attribute__((address_space(3))) void*)(lptr), 16, 0, 0)

// ---------------------------------------------------------------------------
__global__ void mark_k(float* __restrict__ out, float val, int n) {
    int i = blockIdx.x * 256 + threadIdx.x;
    if (i < n) out[i] = val;
}

// ---------------------------------------------------------------------------
// x (f32) -> xb (bf16), vectorized 8/thread.
// ---------------------------------------------------------------------------
__global__ __launch_bounds__(256) void cvt_x_k(const float* __restrict__ src,
                                               bf16* __restrict__ dst, int n) {
    int i = (blockIdx.x * 256 + threadIdx.x) * 8;
    if (i >= n) return;
    float4 a = *(const float4*)&src[i];
    float4 b = *(const float4*)&src[i + 4];
    bf16x8 w;
    w[0] = (bf16)a.x; w[1] = (bf16)a.y; w[2] = (bf16)a.z; w[3] = (bf16)a.w;
    w[4] = (bf16)b.x; w[5] = (bf16)b.y; w[6] = (bf16)b.z; w[7] = (bf16)b.w;
    *(bf16x8*)&dst[i] = w;
}

// ---------------------------------------------------------------------------
// LDS-tiled transpose + f32->bf16: dst[c*R + r] = (bf16)src[r*C + c].
// ---------------------------------------------------------------------------
__global__ __launch_bounds__(256) void transpose_cvt_tiled(
    const float* __restrict__ src, bf16* __restrict__ dst, int R, int C) {
    __shared__ float t[32][33];
    int tid = threadIdx.x, tx = tid & 31, ty = tid >> 5;
    int bx = blockIdx.x * 32, by = blockIdx.y * 32;
#pragma unroll
    for (int i = 0; i < 4; ++i) {
        int row = by + ty + i * 8;
        t[ty + i * 8][tx] = src[(size_t)row * C + bx + tx];
    }
    __syncthreads();
#pragma unroll
    for (int i = 0; i < 4; ++i) {
        int outrow = bx + ty + i * 8;
        dst[(size_t)outrow * R + by + tx] = (bf16)t[tx][ty + i * 8];
    }
}

// ---------------------------------------------------------------------------
// m97-style GEMM body: 128x128 tile, BK=32, unpadded 128x32 LDS tiles,
// global_load_lds width-16 staging (4 issues/iter), 4 waves, 4x4 MFMA/wave.
// A (M x K bf16, K-contig), B (N x K bf16 = B^T).
// ---------------------------------------------------------------------------
#define GEMM_V2_BODY(Aptr, Bptr, Kdim)                                         \
    __shared__ __align__(16) bf16 As[128 * 32];                                \
    __shared__ __align__(16) bf16 Bs[128 * 32];                                \
    int tid = threadIdx.x, lane = tid & 63, wave = tid >> 6;                   \
    int quad = lane >> 4, l16 = lane & 15;                                     \
    int wr = wave >> 1, wc = wave & 1;                                         \
    int m0 = blockIdx.y * 128, n0 = blockIdx.x * 128;                          \
    const f32x4 fz = {0.f, 0.f, 0.f, 0.f};                                     \
    f32x4 acc[4][4];                                                           \
    _Pragma("unroll") for (int mi = 0; mi < 4; ++mi)                           \
        _Pragma("unroll") for (int nj = 0; nj < 4; ++nj) acc[mi][nj] = fz;     \
    const bf16* Ablk = (Aptr) + (size_t)m0 * (Kdim);                           \
    const bf16* Bblk = (Bptr) + (size_t)n0 * (Kdim);                           \
    int grow = tid >> 2;           /* 0..63 */                                 \
    int gcol = (tid & 3) * 8;                                                  \
    for (int k0 = 0; k0 < (Kdim); k0 += 32) {                                  \
        __syncthreads();                                                       \
        _Pragma("unroll") for (int j = 0; j < 2; ++j) {                        \
            const bf16* ga = &Ablk[(size_t)(grow + j * 64) * (Kdim) + k0 + gcol]; \
            const bf16* gb = &Bblk[(size_t)(grow + j * 64) * (Kdim) + k0 + gcol]; \
            GLOAD_LDS16(ga, &As[wave * 512 + j * 2048]);                       \
            GLOAD_LDS16(gb, &Bs[wave * 512 + j * 2048]);                       \
        }                                                                      \
        __syncthreads();                                                       \
        bf16x8 af[4], bfv[4];                                                  \
        _Pragma("unroll") for (int t = 0; t < 4; ++t) {                        \
            af[t]  = *(const bf16x8*)&As[(wr * 64 + t * 16 + l16) * 32 + quad * 8]; \
            bfv[t] = *(const bf16x8*)&Bs[(wc * 64 + t * 16 + l16) * 32 + quad * 8]; \
        }                                                                      \
        _Pragma("unroll") for (int mi = 0; mi < 4; ++mi)                       \
            _Pragma("unroll") for (int nj = 0; nj < 4; ++nj)                   \
                acc[mi][nj] = MFMA16(af[mi], bfv[nj], acc[mi][nj]);            \
    }

// ---------------------------------------------------------------------------
// QKV GEMM v2: A = xb (bf16), B = wqkvT. Fused head-reshape epilogue,
// Q pre-scaled by 0.125.
// ---------------------------------------------------------------------------
__global__ __launch_bounds__(256) void gemm_qkv_v2(
    const bf16* __restrict__ A, const bf16* __restrict__ B,
    const float* __restrict__ bias, bf16* __restrict__ Qh,
    bf16* __restrict__ Kh, bf16* __restrict__ Vth) {
    GEMM_V2_BODY(A, B, 768)
#pragma unroll
    for (int nj = 0; nj < 4; ++nj) {
        int col = n0 + wc * 64 + nj * 16 + l16;
        float bv = bias[col];
        int which = col / 768;
        int rr = col % 768;
        int h = rr >> 6, d = rr & 63;
        float scale = (which == 0) ? 0.125f : 1.0f;
#pragma unroll
        for (int mi = 0; mi < 4; ++mi)
#pragma unroll
            for (int r = 0; r < 4; ++r) {
                int row = m0 + wr * 64 + mi * 16 + quad * 4 + r;
                int b = row >> 11, l = row & 2047;
                size_t bh = (size_t)(b * 12 + h);
                bf16 val = (bf16)((acc[mi][nj][r] + bv) * scale);
                if (which == 0)      Qh[(bh * 2048 + l) * 64 + d] = val;
                else if (which == 1) Kh[(bh * 2048 + l) * 64 + d] = val;
                else                 Vth[(bh * 64 + d) * 2048 + l] = val;
            }
    }
}

// ---------------------------------------------------------------------------
// Out-projection GEMM v2: out(F32) = ctx (bf16) @ woutT^T + b_out.
// ---------------------------------------------------------------------------
__global__ __launch_bounds__(256) void gemm_out_v2(
    const bf16* __restrict__ A, const bf16* __restrict__ B,
    const float* __restrict__ bias, float* __restrict__ C, int N) {
    GEMM_V2_BODY(A, B, 768)
#pragma unroll
    for (int nj = 0; nj < 4; ++nj) {
        int col = n0 + wc * 64 + nj * 16 + l16;
        float bv = bias[col];
#pragma unroll
        for (int mi = 0; mi < 4; ++mi)
#pragma unroll
            for (int r = 0; r < 4; ++r) {
                int row = m0 + wr * 64 + mi * 16 + quad * 4 + r;
                C[(size_t)row * N + col] = acc[mi][nj][r] + bv;
            }
    }
}

// ---------------------------------------------------------------------------
// Flash attention v3 (unchanged from round 12: 85 us, conflicts 2.36e6).
// ---------------------------------------------------------------------------
#define SW(r, c8) ((r) * 64 + (((((c8) >> 3) ^ ((r) & 7))) << 3))
#define PLD 72

__global__ __launch_bounds__(128) void flash_attn(
    const bf16* __restrict__ Q, const bf16* __restrict__ K,
    const bf16* __restrict__ V, const int* __restrict__ mask,
    bf16* __restrict__ ctx) {
    __shared__ __align__(16) bf16 Ks[2][64 * 64];
    __shared__ __align__(16) bf16 Vs[2][64 * 64];
    __shared__ __align__(16) bf16 Ps[2][16 * PLD];
    __shared__ float maskS[2048];

    int tid = threadIdx.x, lane = tid & 63, wave = tid >> 6;
    int quad = lane >> 4, l16 = lane & 15;
    int bh = blockIdx.y, b = bh / 12;
    int q0 = blockIdx.x * 64 + wave * 32;

    bf16x8 aq[2][2];
#pragma unroll
    for (int qt = 0; qt < 2; ++qt) {
        const bf16* Qp = Q + ((size_t)bh * 2048 + q0 + qt * 16 + l16) * 64;
        aq[qt][0] = *(const bf16x8*)(Qp + quad * 8);
        aq[qt][1] = *(const bf16x8*)(Qp + 32 + quad * 8);
    }

    const int* mrow = mask + b * 2048;
#pragma unroll
    for (int i = 0; i < 16; ++i) {
        int idx = i * 128 + tid;
        maskS[idx] = (mrow[idx] != 0) ? 0.0f : NEG_BIG;
    }

    const f32x4 fz = {0.f, 0.f, 0.f, 0.f};
    f32x4 o[2][4];
    float m_i[2], l_i[2];
#pragma unroll
    for (int qt = 0; qt < 2; ++qt) {
        m_i[qt] = NEG_BIG; l_i[qt] = 0.f;
#pragma unroll
        for (int dt = 0; dt < 4; ++dt) o[qt][dt] = fz;
    }

    int srow = tid >> 3;
    int sc8  = (tid & 7) * 8;
    const bf16* Kbase = K + (size_t)bh * 2048 * 64;
    const bf16* Vbase = V + (size_t)bh * 64 * 2048;

#pragma unroll
    for (int i = 0; i < 4; ++i) {
        int row = srow + i * 16;
        *(bf16x8*)&Ks[0][SW(row, sc8)] =
            *(const bf16x8*)&Kbase[(size_t)row * 64 + sc8];
        *(bf16x8*)&Vs[0][SW(row, sc8)] =
            *(const bf16x8*)&Vbase[(size_t)row * 2048 + sc8];
    }

    int p = 0;
    for (int kb = 0; kb < 2048; kb += 64) {
        __syncthreads();

        if (kb + 64 < 2048) {
            int nb = kb + 64;
#pragma unroll
            for (int i = 0; i < 4; ++i) {
                int row = srow + i * 16;
                *(bf16x8*)&Ks[1 - p][SW(row, sc8)] =
                    *(const bf16x8*)&Kbase[(size_t)(nb + row) * 64 + sc8];
                *(bf16x8*)&Vs[1 - p][SW(row, sc8)] =
                    *(const bf16x8*)&Vbase[(size_t)row * 2048 + nb + sc8];
            }
        }

        f32x4 s[2][4];
#pragma unroll
        for (int ct = 0; ct < 4; ++ct) {
            int krow = ct * 16 + l16;
            bf16x8 kf0 = *(const bf16x8*)&Ks[p][SW(krow, quad * 8)];
            bf16x8 kf1 = *(const bf16x8*)&Ks[p][SW(krow, 32 + quad * 8)];
#pragma unroll
            for (int qt = 0; qt < 2; ++qt) {
                f32x4 t = fz;
                t = MFMA16(kf0, aq[qt][0], t);
                t = MFMA16(kf1, aq[qt][1], t);
                s[qt][ct] = t;
            }
        }

#pragma unroll
        for (int ct = 0; ct < 4; ++ct) {
            const float* mk = &maskS[kb + ct * 16 + quad * 4];
            float4 mv = *(const float4*)mk;
            float ma[4] = {mv.x, mv.y, mv.z, mv.w};
#pragma unroll
            for (int qt = 0; qt < 2; ++qt)
#pragma unroll
                for (int r = 0; r < 4; ++r) s[qt][ct][r] += ma[r];
        }

        float alpha[2];
#pragma unroll
        for (int qt = 0; qt < 2; ++qt) {
            float mx = NEG_BIG;
#pragma unroll
            for (int ct = 0; ct < 4; ++ct)
#pragma unroll
                for (int r = 0; r < 4; ++r) mx = fmaxf(mx, s[qt][ct][r]);
            mx = fmaxf(mx, __shfl_xor(mx, 16));
            mx = fmaxf(mx, __shfl_xor(mx, 32));
            float nm = fmaxf(m_i[qt], mx);
            alpha[qt] = __expf(m_i[qt] - nm);
            m_i[qt] = nm;
            float sum = 0.f;
#pragma unroll
            for (int ct = 0; ct < 4; ++ct)
#pragma unroll
                for (int r = 0; r < 4; ++r) {
                    float pv = __expf(s[qt][ct][r] - nm);
                    s[qt][ct][r] = pv;
                    sum += pv;
                }
            sum += __shfl_xor(sum, 16);
            sum += __shfl_xor(sum, 32);
            l_i[qt] = l_i[qt] * alpha[qt] + sum;
        }

#pragma unroll
        for (int qt = 0; qt < 2; ++qt) {
            float ab[4];
#pragma unroll
            for (int r = 0; r < 4; ++r)
                ab[r] = __shfl(alpha[qt], (lane & 48) | (quad * 4 + r));
#pragma unroll
            for (int dt = 0; dt < 4; ++dt)
#pragma unroll
                for (int r = 0; r < 4; ++r) o[qt][dt][r] *= ab[r];
        }

        bf16x8 vf[2][4];
#pragma unroll
        for (int ks = 0; ks < 2; ++ks)
#pragma unroll
            for (int dt = 0; dt < 4; ++dt)
                vf[ks][dt] = *(const bf16x8*)&Vs[p][SW(dt * 16 + l16, ks * 32 + quad * 8)];

#pragma unroll
        for (int qt = 0; qt < 2; ++qt) {
#pragma unroll
            for (int ct = 0; ct < 4; ++ct) {
                bf16x4 pk;
#pragma unroll
                for (int r = 0; r < 4; ++r) pk[r] = (bf16)s[qt][ct][r];
                *(bf16x4*)&Ps[wave][l16 * PLD + ct * 16 + quad * 4] = pk;
            }
#pragma unroll
            for (int ks = 0; ks < 2; ++ks) {
                bf16x8 ap = *(const bf16x8*)&Ps[wave][l16 * PLD + ks * 32 + quad * 8];
#pragma unroll
                for (int dt = 0; dt < 4; ++dt)
                    o[qt][dt] = MFMA16(ap, vf[ks][dt], o[qt][dt]);
            }
        }
        p ^= 1;
    }

    int h = bh % 12;
#pragma unroll
    for (int qt = 0; qt < 2; ++qt) {
        float linv[4];
#pragma unroll
        for (int r = 0; r < 4; ++r)
            linv[r] = 1.0f / __shfl(l_i[qt], (lane & 48) | (quad * 4 + r));
#pragma unroll
        for (int dt = 0; dt < 4; ++dt)
#pragma unroll
            for (int r = 0; r < 4; ++r) {
                int qrow = q0 + qt * 16 + quad * 4 + r;
                ctx[((size_t)b * 2048 + qrow) * 768 + h * 64 + dt * 16 + l16] =
                    (bf16)(o[qt][dt][r] * linv[r]);
            }
    }
}

// ---------------------------------------------------------------------------
extern "C" void kernel_launch(void* const* d_in, const int* in_sizes, int n_in,
                              void* d_out, int out_size, void* d_ws, size_t ws_size,
                              hipStream_t stream) {
    float* out = (float*)d_out;   // f32 output (validated round 10)

    const float* x = nullptr; const int* mask = nullptr;
    const float* w_qkv = nullptr; const float* b_qkv = nullptr;
    const float* w_out = nullptr; const float* b_out = nullptr;
    int found = 0;
    for (int i = 0; i < n_in; ++i) {
        switch (in_sizes[i]) {
            case 3145728: x     = (const float*)d_in[i]; found |= 1;  break;
            case 4096:    mask  = (const int*)  d_in[i]; found |= 2;  break;
            case 1769472: w_qkv = (const float*)d_in[i]; found |= 4;  break;
            case 2304:    b_qkv = (const float*)d_in[i]; found |= 8;  break;
            case 589824:  w_out = (const float*)d_in[i]; found |= 16; break;
            case 768:     b_out = (const float*)d_in[i]; found |= 32; break;
        }
    }
    if (found != 63) {
        mark_k<<<(out_size + 255) / 256, 256, 0, stream>>>(
            out, 200.0f + (float)found, out_size);
        return;
    }

    const int M = 4096, D = 768, N3 = 2304;
    const size_t HEADS_ELEMS = (size_t)24 * 2048 * 64;  // 3,145,728

    // Workspace (23.6 MB, proven). d_out (12.6 MB) moonlights as Qh + xb.
    bf16* ws    = (bf16*)d_ws;
    bf16* Kh    = ws;
    bf16* Vth   = Kh + HEADS_ELEMS;
    bf16* ctx   = Vth + HEADS_ELEMS;
    bf16* wqkvT = ctx + (size_t)M * D;
    bf16* woutT = wqkvT + (size_t)N3 * D;
    bf16* Qh    = (bf16*)d_out;                 // first half of d_out
    bf16* xb    = (bf16*)d_out + HEADS_ELEMS;   // second half of d_out

    cvt_x_k<<<(M * D / 8 + 255) / 256, 256, 0, stream>>>(x, xb, M * D);
    transpose_cvt_tiled<<<dim3(2304 / 32, 768 / 32), 256, 0, stream>>>(
        w_qkv, wqkvT, 768, 2304);
    transpose_cvt_tiled<<<dim3(768 / 32, 768 / 32), 256, 0, stream>>>(
        w_out, woutT, 768, 768);

    gemm_qkv_v2<<<dim3(N3 / 128, M / 128), 256, 0, stream>>>(
        xb, wqkvT, b_qkv, Qh, Kh, Vth);

    flash_attn<<<dim3(2048 / 64, 24), 128, 0, stream>>>(Qh, Kh, Vth, mask, ctx);

    gemm_out_v2<<<dim3(D / 128, M / 128), 256, 0, stream>>>(
        ctx, woutT, b_out, out, D);
}